// Round 1
// baseline (486.089 us; speedup 1.0000x reference)
//
#include <hip/hip_runtime.h>
#include <hip/hip_bf16.h>

using bf16x8 = __attribute__((ext_vector_type(8))) short;
using f32x4  = __attribute__((ext_vector_type(4))) float;
typedef unsigned short u16;

#define SEQ_TOT 32768   // 8*4096
#define NCHUNK  64      // 8*8
#define SQRT128 11.313708498984761f

__device__ __forceinline__ u16 f2bf(float f) {
  unsigned u = __builtin_bit_cast(unsigned, f);
  u += 0x7fffu + ((u >> 16) & 1u);
  return (u16)(u >> 16);
}

__device__ __forceinline__ float swishf(float c) {
  return c / (1.0f + __expf(-c));
}

// ---------------- prep kernels ----------------
__global__ __launch_bounds__(256) void prep_wqkt(const float* __restrict__ Wqk,
                                                 u16* __restrict__ Wqkt) {
  int t = blockIdx.x * 256 + threadIdx.x;   // n*1024 + k, 128*1024
  int n = t >> 10, k = t & 1023;
  Wqkt[t] = f2bf(Wqk[(size_t)k * 128 + n]);
}

__global__ __launch_bounds__(256) void prep_wvt(const float* __restrict__ Wv,
                                                u16* __restrict__ Wvt) {
  int t = blockIdx.x * 256 + threadIdx.x;   // n*1024 + k, 1024*1024
  int n = t >> 10, k = t & 1023;
  Wvt[t] = f2bf(Wv[(size_t)k * 1024 + n]);
}

__global__ __launch_bounds__(512) void prep_bias(const float* __restrict__ rel_emb,
                                                 float* __restrict__ bias_tab) {
  int d = threadIdx.x;  // 0..511  (d = i - j >= 0)
  int b;
  if (d < 16) {
    b = d;
  } else {
    float v = 16.0f + __logf((float)d * 0.0625f) * (16.0f / 2.0794415416798357f);
    b = (int)v;
    if (b > 31) b = 31;
  }
  bias_tab[d] = rel_emb[b] * SQRT128;
}

// ---------------- fused projection GEMM ----------------
// grid: (256 m-blocks, 9 n-blocks), block 256 (4 waves, 2x2 of 64x64)
// nb==0: C cols 0..127 -> q,k (gamma/beta).  nb>=1: v cols (nb-1)*128.. -> v_t transposed.
__global__ __launch_bounds__(256, 2) void proj_kernel(
    const float* __restrict__ x,
    const u16* __restrict__ Wqkt, const u16* __restrict__ Wvt,
    const float* __restrict__ bqk, const float* __restrict__ bv,
    const float* __restrict__ gamma, const float* __restrict__ beta,
    u16* __restrict__ qm, u16* __restrict__ km, u16* __restrict__ vt) {
  __shared__ u16 a_lds[128][40];
  __shared__ u16 b_lds[128][40];
  const int tid = threadIdx.x;
  const int lane = tid & 63;
  const int wid = tid >> 6;
  const int wm = wid >> 1, wn = wid & 1;
  const int m0 = blockIdx.x * 128;
  const int nb = blockIdx.y;
  const u16* Wt = (nb == 0) ? Wqkt : (Wvt + (size_t)(nb - 1) * 128 * 1024);

  f32x4 acc[4][4];
#pragma unroll
  for (int i = 0; i < 4; i++)
#pragma unroll
    for (int j = 0; j < 4; j++) acc[i][j] = f32x4{0.f, 0.f, 0.f, 0.f};

  const int srow = tid >> 1;
  const int shalf = (tid & 1) * 16;

  for (int kt = 0; kt < 32; ++kt) {
    const int k0 = kt * 32;
    __syncthreads();
    {  // stage A (fp32 -> bf16)
      const float* src = x + (size_t)(m0 + srow) * 1024 + k0 + shalf;
      float4 f0 = *(const float4*)(src);
      float4 f1 = *(const float4*)(src + 4);
      float4 f2 = *(const float4*)(src + 8);
      float4 f3 = *(const float4*)(src + 12);
      uint4 p0, p1;
      p0.x = f2bf(f0.x) | ((unsigned)f2bf(f0.y) << 16);
      p0.y = f2bf(f0.z) | ((unsigned)f2bf(f0.w) << 16);
      p0.z = f2bf(f1.x) | ((unsigned)f2bf(f1.y) << 16);
      p0.w = f2bf(f1.z) | ((unsigned)f2bf(f1.w) << 16);
      p1.x = f2bf(f2.x) | ((unsigned)f2bf(f2.y) << 16);
      p1.y = f2bf(f2.z) | ((unsigned)f2bf(f2.w) << 16);
      p1.z = f2bf(f3.x) | ((unsigned)f2bf(f3.y) << 16);
      p1.w = f2bf(f3.z) | ((unsigned)f2bf(f3.w) << 16);
      *(uint4*)&a_lds[srow][shalf] = p0;
      *(uint4*)&a_lds[srow][shalf + 8] = p1;
    }
    {  // stage B (already bf16)
      const u16* src = Wt + (size_t)srow * 1024 + k0 + shalf;
      uint4 w0 = *(const uint4*)(src);
      uint4 w1 = *(const uint4*)(src + 8);
      *(uint4*)&b_lds[srow][shalf] = w0;
      *(uint4*)&b_lds[srow][shalf + 8] = w1;
    }
    __syncthreads();
    bf16x8 af[4], bfr[4];
#pragma unroll
    for (int mi = 0; mi < 4; mi++)
      af[mi] = *(const bf16x8*)&a_lds[wm * 64 + mi * 16 + (lane & 15)][8 * (lane >> 4)];
#pragma unroll
    for (int ni = 0; ni < 4; ni++)
      bfr[ni] = *(const bf16x8*)&b_lds[wn * 64 + ni * 16 + (lane & 15)][8 * (lane >> 4)];
#pragma unroll
    for (int mi = 0; mi < 4; mi++)
#pragma unroll
      for (int ni = 0; ni < 4; ni++)
        acc[mi][ni] = __builtin_amdgcn_mfma_f32_16x16x32_bf16(af[mi], bfr[ni], acc[mi][ni], 0, 0, 0);
  }

  if (nb == 0) {
#pragma unroll
    for (int ni = 0; ni < 4; ni++) {
      const int nn = wn * 64 + ni * 16 + (lane & 15);
      const float bb = bqk[nn];
      const float g0 = gamma[nn], g1 = gamma[128 + nn];
      const float be0 = beta[nn], be1 = beta[128 + nn];
#pragma unroll
      for (int mi = 0; mi < 4; mi++) {
#pragma unroll
        for (int r = 0; r < 4; r++) {
          const int m = m0 + wm * 64 + mi * 16 + (lane >> 4) * 4 + r;
          const float s = swishf(acc[mi][ni][r] + bb);
          qm[(size_t)m * 128 + nn] = f2bf(s * g0 + be0);
          km[(size_t)m * 128 + nn] = f2bf(s * g1 + be1);
        }
      }
    }
  } else {
#pragma unroll
    for (int ni = 0; ni < 4; ni++) {
      const int z = (nb - 1) * 128 + wn * 64 + ni * 16 + (lane & 15);
      const float bb = bv[z];
#pragma unroll
      for (int mi = 0; mi < 4; mi++) {
        const int m = m0 + wm * 64 + mi * 16 + (lane >> 4) * 4;
        const int chunkid = m >> 9;
        const int j = m & 511;
        ushort4 pk;
        pk.x = f2bf(swishf(acc[mi][ni][0] + bb));
        pk.y = f2bf(swishf(acc[mi][ni][1] + bb));
        pk.z = f2bf(swishf(acc[mi][ni][2] + bb));
        pk.w = f2bf(swishf(acc[mi][ni][3] + bb));
        *(ushort4*)&vt[((size_t)chunkid * 1024 + z) * 512 + j] = pk;
      }
    }
  }
}

// ---------------- scores + softmax -> P ----------------
// grid: (8 q-tiles, 64 chunks), block 256 (4 waves, each 16 q-rows x 512 cols)
__global__ __launch_bounds__(256, 2) void score_kernel(
    const u16* __restrict__ qm, const u16* __restrict__ km,
    const float* __restrict__ bias_tab, u16* __restrict__ P) {
  __shared__ u16 k_lds[64][136];
  const int tid = threadIdx.x;
  const int lane = tid & 63;
  const int wid = tid >> 6;
  const int qt = blockIdx.x;   // 0..7
  const int ch = blockIdx.y;   // 0..63

  bf16x8 qf[4];
  {
    const int r = ch * 512 + qt * 64 + wid * 16 + (lane & 15);
    const u16* qp = qm + (size_t)r * 128 + 8 * (lane >> 4);
#pragma unroll
    for (int kk = 0; kk < 4; kk++) qf[kk] = *(const bf16x8*)(qp + kk * 32);
  }

  f32x4 acc[32];
#pragma unroll
  for (int i = 0; i < 32; i++) acc[i] = f32x4{0.f, 0.f, 0.f, 0.f};

  const int srow = tid >> 2;
  const int soff = (tid & 3) * 32;

#pragma unroll
  for (int kt = 0; kt < 8; ++kt) {
    if (kt <= qt) {
      __syncthreads();
      {
        const u16* src = km + (size_t)(ch * 512 + kt * 64 + srow) * 128 + soff;
        uint4 w0 = *(const uint4*)(src);
        uint4 w1 = *(const uint4*)(src + 8);
        uint4 w2 = *(const uint4*)(src + 16);
        uint4 w3 = *(const uint4*)(src + 24);
        *(uint4*)&k_lds[srow][soff] = w0;
        *(uint4*)&k_lds[srow][soff + 8] = w1;
        *(uint4*)&k_lds[srow][soff + 16] = w2;
        *(uint4*)&k_lds[srow][soff + 24] = w3;
      }
      __syncthreads();
#pragma unroll
      for (int jt = 0; jt < 4; jt++) {
#pragma unroll
        for (int kk = 0; kk < 4; kk++) {
          bf16x8 bfr = *(const bf16x8*)&k_lds[jt * 16 + (lane & 15)][kk * 32 + 8 * (lane >> 4)];
          acc[kt * 4 + jt] =
              __builtin_amdgcn_mfma_f32_16x16x32_bf16(qf[kk], bfr, acc[kt * 4 + jt], 0, 0, 0);
        }
      }
    }
  }

  const float scale = 0.03125f;  // 1024^-0.5
  const int jbase = lane & 15;
  const int nct = (qt + 1) * 4;

#pragma unroll
  for (int r = 0; r < 4; r++) {
    const int i = qt * 64 + wid * 16 + (lane >> 4) * 4 + r;
    float mx = -INFINITY;
#pragma unroll
    for (int ct = 0; ct < 32; ++ct) {
      if (ct < nct) {
        const int j = ct * 16 + jbase;
        float val = (j <= i) ? (acc[ct][r] * scale + bias_tab[i - j]) : -INFINITY;
        acc[ct][r] = val;
        mx = fmaxf(mx, val);
      }
    }
#pragma unroll
    for (int d = 1; d < 16; d <<= 1) mx = fmaxf(mx, __shfl_xor(mx, d));
    float sum = 0.f;
#pragma unroll
    for (int ct = 0; ct < 32; ++ct) {
      if (ct < nct) {
        float e = __expf(acc[ct][r] - mx);
        acc[ct][r] = e;
        sum += e;
      }
    }
#pragma unroll
    for (int d = 1; d < 16; d <<= 1) sum += __shfl_xor(sum, d);
    const float inv = 1.0f / sum;
    const size_t base = ((size_t)ch * 512 + i) * 512;
#pragma unroll
    for (int ct = 0; ct < 32; ++ct) {
      u16 pv = (ct < nct) ? f2bf(acc[ct][r] * inv) : (u16)0;
      P[base + ct * 16 + jbase] = pv;
    }
  }
}

// ---------------- out = P @ V ----------------
// grid: (4 m-blocks, 8 n-blocks, 64 chunks), block 256 (4 waves, 2x2 of 64x64)
__global__ __launch_bounds__(256, 2) void out_kernel(
    const u16* __restrict__ P, const u16* __restrict__ vt,
    float* __restrict__ out) {
  __shared__ u16 a_lds[128][40];
  __shared__ u16 b_lds[128][40];
  const int tid = threadIdx.x;
  const int lane = tid & 63;
  const int wid = tid >> 6;
  const int wm = wid >> 1, wn = wid & 1;
  const int mb = blockIdx.x;   // 0..3
  const int nb = blockIdx.y;   // 0..7
  const int ch = blockIdx.z;   // 0..63
  const u16* Ab = P + (size_t)ch * 512 * 512 + (size_t)mb * 128 * 512;
  const u16* Bb = vt + (size_t)ch * 1024 * 512 + (size_t)nb * 128 * 512;

  f32x4 acc[4][4];
#pragma unroll
  for (int i = 0; i < 4; i++)
#pragma unroll
    for (int j = 0; j < 4; j++) acc[i][j] = f32x4{0.f, 0.f, 0.f, 0.f};

  const int srow = tid >> 1;
  const int shalf = (tid & 1) * 16;
  const int kend = (mb + 1) * 4;  // causal: P cols beyond are zero

  for (int kt = 0; kt < kend; ++kt) {
    const int k0 = kt * 32;
    __syncthreads();
    {
      const u16* s = Ab + (size_t)srow * 512 + k0 + shalf;
      uint4 w0 = *(const uint4*)(s);
      uint4 w1 = *(const uint4*)(s + 8);
      *(uint4*)&a_lds[srow][shalf] = w0;
      *(uint4*)&a_lds[srow][shalf + 8] = w1;
    }
    {
      const u16* s = Bb + (size_t)srow * 512 + k0 + shalf;
      uint4 w0 = *(const uint4*)(s);
      uint4 w1 = *(const uint4*)(s + 8);
      *(uint4*)&b_lds[srow][shalf] = w0;
      *(uint4*)&b_lds[srow][shalf + 8] = w1;
    }
    __syncthreads();
    bf16x8 af[4], bfr[4];
#pragma unroll
    for (int mi = 0; mi < 4; mi++)
      af[mi] = *(const bf16x8*)&a_lds[wm * 64 + mi * 16 + (lane & 15)][8 * (lane >> 4)];
#pragma unroll
    for (int ni = 0; ni < 4; ni++)
      bfr[ni] = *(const bf16x8*)&b_lds[wn * 64 + ni * 16 + (lane & 15)][8 * (lane >> 4)];
#pragma unroll
    for (int mi = 0; mi < 4; mi++)
#pragma unroll
      for (int ni = 0; ni < 4; ni++)
        acc[mi][ni] = __builtin_amdgcn_mfma_f32_16x16x32_bf16(af[mi], bfr[ni], acc[mi][ni], 0, 0, 0);
  }

#pragma unroll
  for (int ni = 0; ni < 4; ni++) {
    const int z = nb * 128 + wn * 64 + ni * 16 + (lane & 15);
#pragma unroll
    for (int mi = 0; mi < 4; mi++) {
#pragma unroll
      for (int r = 0; r < 4; r++) {
        const int i = mb * 128 + wm * 64 + mi * 16 + (lane >> 4) * 4 + r;
        out[((size_t)ch * 512 + i) * 1024 + z] = acc[mi][ni][r];
      }
    }
  }
}

// ---------------- launch ----------------
extern "C" void kernel_launch(void* const* d_in, const int* in_sizes, int n_in,
                              void* d_out, int out_size, void* d_ws, size_t ws_size,
                              hipStream_t stream) {
  const float* x = (const float*)d_in[0];
  const float* Wqk = (const float*)d_in[1];
  const float* bqk = (const float*)d_in[2];
  const float* Wv = (const float*)d_in[3];
  const float* bv = (const float*)d_in[4];
  const float* gamma = (const float*)d_in[5];
  const float* beta = (const float*)d_in[6];
  const float* rel_emb = (const float*)d_in[7];

  char* ws = (char*)d_ws;
  u16* Wqkt = (u16*)(ws + 0);                    //   262144 B
  u16* Wvt = (u16*)(ws + 262144);                //  2097152 B
  float* bias_tab = (float*)(ws + 2359296);      //     2048 B
  u16* qm = (u16*)(ws + 2361344);                //  8388608 B
  u16* km = (u16*)(ws + 10749952);               //  8388608 B
  u16* vt = (u16*)(ws + 19138560);               // 67108864 B
  u16* P = (u16*)(ws + 86247424);                // 33554432 B  -> total 119801856 B
  float* out = (float*)d_out;

  prep_wqkt<<<512, 256, 0, stream>>>(Wqk, Wqkt);
  prep_wvt<<<4096, 256, 0, stream>>>(Wv, Wvt);
  prep_bias<<<1, 512, 0, stream>>>(rel_emb, bias_tab);
  proj_kernel<<<dim3(256, 9), 256, 0, stream>>>(x, Wqkt, Wvt, bqk, bv, gamma, beta, qm, km, vt);
  score_kernel<<<dim3(8, 64), 256, 0, stream>>>(qm, km, bias_tab, P);
  out_kernel<<<dim3(4, 8, 64), 256, 0, stream>>>(P, vt, out);
}

// Round 2
// 466.554 us; speedup vs baseline: 1.0419x; 1.0419x over previous
//
#include <hip/hip_runtime.h>
#include <hip/hip_bf16.h>

using bf16x8 = __attribute__((ext_vector_type(8))) short;
using f32x4  = __attribute__((ext_vector_type(4))) float;
typedef unsigned short u16;

#define SQRT128 11.313708498984761f

__device__ __forceinline__ u16 f2bf(float f) {
  unsigned u = __builtin_bit_cast(unsigned, f);
  u += 0x7fffu + ((u >> 16) & 1u);
  return (u16)(u >> 16);
}

__device__ __forceinline__ float swishf(float c) {
  return c / (1.0f + __expf(-c));
}

__device__ __forceinline__ void gld16(const void* g, void* l) {
  __builtin_amdgcn_global_load_lds((const __attribute__((address_space(1))) unsigned*)g,
                                   (__attribute__((address_space(3))) unsigned*)l, 16, 0, 0);
}

// ---------------- prep kernels ----------------
__global__ __launch_bounds__(256) void prep_xb(const float* __restrict__ x,
                                               u16* __restrict__ xb) {
  size_t t = ((size_t)blockIdx.x * 256 + threadIdx.x) * 8;
  float4 f0 = *(const float4*)(x + t);
  float4 f1 = *(const float4*)(x + t + 4);
  uint4 p;
  p.x = f2bf(f0.x) | ((unsigned)f2bf(f0.y) << 16);
  p.y = f2bf(f0.z) | ((unsigned)f2bf(f0.w) << 16);
  p.z = f2bf(f1.x) | ((unsigned)f2bf(f1.y) << 16);
  p.w = f2bf(f1.z) | ((unsigned)f2bf(f1.w) << 16);
  *(uint4*)(xb + t) = p;
}

__global__ __launch_bounds__(256) void prep_wqkt(const float* __restrict__ Wqk,
                                                 u16* __restrict__ Wqkt) {
  int t = blockIdx.x * 256 + threadIdx.x;   // n*1024 + k
  int n = t >> 10, k = t & 1023;
  Wqkt[t] = f2bf(Wqk[(size_t)k * 128 + n]);
}

__global__ __launch_bounds__(256) void prep_wvt(const float* __restrict__ Wv,
                                                u16* __restrict__ Wvt) {
  int t = blockIdx.x * 256 + threadIdx.x;   // n*1024 + k
  int n = t >> 10, k = t & 1023;
  Wvt[t] = f2bf(Wv[(size_t)k * 1024 + n]);
}

__global__ __launch_bounds__(512) void prep_bias(const float* __restrict__ rel_emb,
                                                 float* __restrict__ bias_tab) {
  int d = threadIdx.x;  // d = i - j >= 0
  int b;
  if (d < 16) {
    b = d;
  } else {
    float v = 16.0f + __logf((float)d * 0.0625f) * (16.0f / 2.0794415416798357f);
    b = (int)v;
    if (b > 31) b = 31;
  }
  bias_tab[d] = rel_emb[b] * SQRT128;
}

// ---------------- fused projection GEMM (m97 structure) ----------------
// grid: (9 n-blocks, 256 m-blocks), block 256 (4 waves, 2x2 of 64x64)
// A,B staged via global_load_lds into linear LDS; XOR swizzle (row&7)<<4 applied
// by pre-swizzling the global source byte-column; ds_read applies same XOR.
__global__ __launch_bounds__(256, 2) void proj_kernel(
    const u16* __restrict__ xb,
    const u16* __restrict__ Wqkt, const u16* __restrict__ Wvt,
    const float* __restrict__ bqk, const float* __restrict__ bv,
    const float* __restrict__ gamma, const float* __restrict__ beta,
    u16* __restrict__ qm, u16* __restrict__ km, u16* __restrict__ vt) {
  __shared__ u16 a_lds[128 * 64];
  __shared__ u16 b_lds[128 * 64];
  const int tid = threadIdx.x;
  const int lane = tid & 63;
  const int w = tid >> 6;
  const int wm = w >> 1, wn = w & 1;
  const int nb = blockIdx.x;
  const int m0 = blockIdx.y * 128;
  const u16* Wt = (nb == 0) ? Wqkt : (Wvt + (size_t)(nb - 1) * 128 * 1024);

  f32x4 acc[4][4];
#pragma unroll
  for (int i = 0; i < 4; i++)
#pragma unroll
    for (int j = 0; j < 4; j++) acc[i][j] = f32x4{0.f, 0.f, 0.f, 0.f};

  // staging geometry: issue i, wave w covers LDS bytes [(i*4+w)*1024, +1024)
  const int srow_sub = w * 8 + (lane >> 3);       // + i*32 = row
  const int sbyte = (lane & 7) * 16;              // byte-in-row pre-swizzle

  for (int kt = 0; kt < 16; ++kt) {
    const int k0 = kt * 64;
    __syncthreads();
#pragma unroll
    for (int i = 0; i < 4; ++i) {
      const int row = i * 32 + srow_sub;
      const int colb = sbyte ^ ((row & 7) << 4);
      gld16(xb + (size_t)(m0 + row) * 1024 + k0 + (colb >> 1), &a_lds[(i * 4 + w) * 512]);
      gld16(Wt + (size_t)row * 1024 + k0 + (colb >> 1), &b_lds[(i * 4 + w) * 512]);
    }
    __syncthreads();
#pragma unroll
    for (int kk = 0; kk < 2; ++kk) {
      bf16x8 af[4], bfr[4];
#pragma unroll
      for (int mi = 0; mi < 4; mi++) {
        const int row = wm * 64 + mi * 16 + (lane & 15);
        const int byte_ = (kk * 64 + (lane >> 4) * 16) ^ ((row & 7) << 4);
        af[mi] = *(const bf16x8*)((const char*)a_lds + row * 128 + byte_);
      }
#pragma unroll
      for (int ni = 0; ni < 4; ni++) {
        const int row = wn * 64 + ni * 16 + (lane & 15);
        const int byte_ = (kk * 64 + (lane >> 4) * 16) ^ ((row & 7) << 4);
        bfr[ni] = *(const bf16x8*)((const char*)b_lds + row * 128 + byte_);
      }
#pragma unroll
      for (int mi = 0; mi < 4; mi++)
#pragma unroll
        for (int ni = 0; ni < 4; ni++)
          acc[mi][ni] = __builtin_amdgcn_mfma_f32_16x16x32_bf16(af[mi], bfr[ni], acc[mi][ni], 0, 0, 0);
    }
  }

  if (nb == 0) {
#pragma unroll
    for (int ni = 0; ni < 4; ni++) {
      const int nn = wn * 64 + ni * 16 + (lane & 15);
      const float bb = bqk[nn];
      const float g0 = gamma[nn], g1 = gamma[128 + nn];
      const float be0 = beta[nn], be1 = beta[128 + nn];
#pragma unroll
      for (int mi = 0; mi < 4; mi++) {
#pragma unroll
        for (int r = 0; r < 4; r++) {
          const int m = m0 + wm * 64 + mi * 16 + (lane >> 4) * 4 + r;
          const float s = swishf(acc[mi][ni][r] + bb);
          qm[(size_t)m * 128 + nn] = f2bf(s * g0 + be0);
          km[(size_t)m * 128 + nn] = f2bf(s * g1 + be1);
        }
      }
    }
  } else {
#pragma unroll
    for (int ni = 0; ni < 4; ni++) {
      const int z = (nb - 1) * 128 + wn * 64 + ni * 16 + (lane & 15);
      const float bb = bv[z];
#pragma unroll
      for (int mi = 0; mi < 4; mi++) {
        const int m = m0 + wm * 64 + mi * 16 + (lane >> 4) * 4;
        const int chunkid = m >> 9;
        const int j = m & 511;
        ushort4 pk;
        pk.x = f2bf(swishf(acc[mi][ni][0] + bb));
        pk.y = f2bf(swishf(acc[mi][ni][1] + bb));
        pk.z = f2bf(swishf(acc[mi][ni][2] + bb));
        pk.w = f2bf(swishf(acc[mi][ni][3] + bb));
        *(ushort4*)&vt[((size_t)chunkid * 1024 + z) * 512 + j] = pk;
      }
    }
  }
}

// ---------------- scores + softmax -> P (swapped operands) ----------------
// grid: (8 q-tiles, 64 chunks), block 256 (4 waves, each 16 q-rows x 512 cols)
// acc[ct][r] = sim[i][j], i = qt*64+wid*16+(lane&15), j = ct*16+(lane>>4)*4+r
__global__ __launch_bounds__(256, 2) void score_kernel(
    const u16* __restrict__ qm, const u16* __restrict__ km,
    const float* __restrict__ bias_tab, u16* __restrict__ P) {
  __shared__ u16 k_lds[64][136];
  const int tid = threadIdx.x;
  const int lane = tid & 63;
  const int wid = tid >> 6;
  const int qt = blockIdx.x;   // 0..7
  const int ch = blockIdx.y;   // 0..63

  bf16x8 qf[4];
  {
    const int r = ch * 512 + qt * 64 + wid * 16 + (lane & 15);
    const u16* qp = qm + (size_t)r * 128 + 8 * (lane >> 4);
#pragma unroll
    for (int kk = 0; kk < 4; kk++) qf[kk] = *(const bf16x8*)(qp + kk * 32);
  }

  f32x4 acc[32];
#pragma unroll
  for (int i = 0; i < 32; i++) acc[i] = f32x4{0.f, 0.f, 0.f, 0.f};

  const int srow = tid >> 2;
  const int soff = (tid & 3) * 32;

#pragma unroll
  for (int kt = 0; kt < 8; ++kt) {
    if (kt <= qt) {
      __syncthreads();
      {
        const u16* src = km + (size_t)(ch * 512 + kt * 64 + srow) * 128 + soff;
        uint4 w0 = *(const uint4*)(src);
        uint4 w1 = *(const uint4*)(src + 8);
        uint4 w2 = *(const uint4*)(src + 16);
        uint4 w3 = *(const uint4*)(src + 24);
        *(uint4*)&k_lds[srow][soff] = w0;
        *(uint4*)&k_lds[srow][soff + 8] = w1;
        *(uint4*)&k_lds[srow][soff + 16] = w2;
        *(uint4*)&k_lds[srow][soff + 24] = w3;
      }
      __syncthreads();
#pragma unroll
      for (int jt = 0; jt < 4; jt++) {
#pragma unroll
        for (int kk = 0; kk < 4; kk++) {
          bf16x8 kf = *(const bf16x8*)&k_lds[jt * 16 + (lane & 15)][kk * 32 + 8 * (lane >> 4)];
          acc[kt * 4 + jt] =
              __builtin_amdgcn_mfma_f32_16x16x32_bf16(kf, qf[kk], acc[kt * 4 + jt], 0, 0, 0);
        }
      }
    }
  }

  const float scale = 0.03125f;  // 1024^-0.5
  const int i = qt * 64 + wid * 16 + (lane & 15);
  const int jb = (lane >> 4) * 4;
  const int nct = (qt + 1) * 4;

  float mx = -INFINITY;
#pragma unroll
  for (int ct = 0; ct < 32; ++ct) {
    if (ct < nct) {
#pragma unroll
      for (int r = 0; r < 4; r++) {
        const int j = ct * 16 + jb + r;
        float val = (j <= i) ? (acc[ct][r] * scale + bias_tab[i - j]) : -INFINITY;
        acc[ct][r] = val;
        mx = fmaxf(mx, val);
      }
    }
  }
  mx = fmaxf(mx, __shfl_xor(mx, 16));
  mx = fmaxf(mx, __shfl_xor(mx, 32));
  float sum = 0.f;
#pragma unroll
  for (int ct = 0; ct < 32; ++ct) {
    if (ct < nct) {
#pragma unroll
      for (int r = 0; r < 4; r++) {
        float e = __expf(acc[ct][r] - mx);
        acc[ct][r] = e;
        sum += e;
      }
    }
  }
  sum += __shfl_xor(sum, 16);
  sum += __shfl_xor(sum, 32);
  const float inv = 1.0f / sum;
  const size_t base = ((size_t)ch * 512 + i) * 512 + jb;
#pragma unroll
  for (int ct = 0; ct < 32; ++ct) {
    ushort4 pk;
    if (ct < nct) {
      pk.x = f2bf(acc[ct][0] * inv);
      pk.y = f2bf(acc[ct][1] * inv);
      pk.z = f2bf(acc[ct][2] * inv);
      pk.w = f2bf(acc[ct][3] * inv);
    } else {
      pk.x = pk.y = pk.z = pk.w = 0;
    }
    *(ushort4*)&P[base + ct * 16] = pk;
  }
}

// ---------------- out = P @ V (m97 structure) ----------------
// grid: (4 m-blocks, 8 n-blocks, 64 chunks), block 256 (4 waves, 2x2 of 64x64)
__global__ __launch_bounds__(256, 2) void out_kernel(
    const u16* __restrict__ P, const u16* __restrict__ vt,
    float* __restrict__ out) {
  __shared__ u16 a_lds[128 * 64];
  __shared__ u16 b_lds[128 * 64];
  const int tid = threadIdx.x;
  const int lane = tid & 63;
  const int w = tid >> 6;
  const int wm = w >> 1, wn = w & 1;
  const int mb = blockIdx.x;   // 0..3
  const int nb = blockIdx.y;   // 0..7
  const int ch = blockIdx.z;   // 0..63
  const u16* Ab = P + (size_t)ch * 512 * 512 + (size_t)mb * 128 * 512;
  const u16* Bb = vt + (size_t)ch * 1024 * 512 + (size_t)nb * 128 * 512;

  f32x4 acc[4][4];
#pragma unroll
  for (int i = 0; i < 4; i++)
#pragma unroll
    for (int j = 0; j < 4; j++) acc[i][j] = f32x4{0.f, 0.f, 0.f, 0.f};

  const int srow_sub = w * 8 + (lane >> 3);
  const int sbyte = (lane & 7) * 16;
  const int kend = (mb + 1) * 2;  // causal: BK=64 tiles

  for (int kt = 0; kt < kend; ++kt) {
    const int k0 = kt * 64;
    __syncthreads();
#pragma unroll
    for (int i = 0; i < 4; ++i) {
      const int row = i * 32 + srow_sub;
      const int colb = sbyte ^ ((row & 7) << 4);
      gld16(Ab + (size_t)row * 512 + k0 + (colb >> 1), &a_lds[(i * 4 + w) * 512]);
      gld16(Bb + (size_t)row * 512 + k0 + (colb >> 1), &b_lds[(i * 4 + w) * 512]);
    }
    __syncthreads();
#pragma unroll
    for (int kk = 0; kk < 2; ++kk) {
      bf16x8 af[4], bfr[4];
#pragma unroll
      for (int mi = 0; mi < 4; mi++) {
        const int row = wm * 64 + mi * 16 + (lane & 15);
        const int byte_ = (kk * 64 + (lane >> 4) * 16) ^ ((row & 7) << 4);
        af[mi] = *(const bf16x8*)((const char*)a_lds + row * 128 + byte_);
      }
#pragma unroll
      for (int ni = 0; ni < 4; ni++) {
        const int row = wn * 64 + ni * 16 + (lane & 15);
        const int byte_ = (kk * 64 + (lane >> 4) * 16) ^ ((row & 7) << 4);
        bfr[ni] = *(const bf16x8*)((const char*)b_lds + row * 128 + byte_);
      }
#pragma unroll
      for (int mi = 0; mi < 4; mi++)
#pragma unroll
        for (int ni = 0; ni < 4; ni++)
          acc[mi][ni] = __builtin_amdgcn_mfma_f32_16x16x32_bf16(af[mi], bfr[ni], acc[mi][ni], 0, 0, 0);
    }
  }

#pragma unroll
  for (int ni = 0; ni < 4; ni++) {
    const int z = nb * 128 + wn * 64 + ni * 16 + (lane & 15);
#pragma unroll
    for (int mi = 0; mi < 4; mi++) {
#pragma unroll
      for (int r = 0; r < 4; r++) {
        const int i = mb * 128 + wm * 64 + mi * 16 + (lane >> 4) * 4 + r;
        out[((size_t)ch * 512 + i) * 1024 + z] = acc[mi][ni][r];
      }
    }
  }
}

// ---------------- launch ----------------
extern "C" void kernel_launch(void* const* d_in, const int* in_sizes, int n_in,
                              void* d_out, int out_size, void* d_ws, size_t ws_size,
                              hipStream_t stream) {
  const float* x = (const float*)d_in[0];
  const float* Wqk = (const float*)d_in[1];
  const float* bqk = (const float*)d_in[2];
  const float* Wv = (const float*)d_in[3];
  const float* bv = (const float*)d_in[4];
  const float* gamma = (const float*)d_in[5];
  const float* beta = (const float*)d_in[6];
  const float* rel_emb = (const float*)d_in[7];

  char* ws = (char*)d_ws;
  u16* Wqkt = (u16*)(ws + 0);                    //   262144 B
  u16* Wvt = (u16*)(ws + 262144);                //  2097152 B
  float* bias_tab = (float*)(ws + 2359296);      //     2048 B
  u16* qm = (u16*)(ws + 2361344);                //  8388608 B
  u16* km = (u16*)(ws + 10749952);               //  8388608 B
  u16* vt = (u16*)(ws + 19138560);               // 67108864 B
  u16* P = (u16*)(ws + 86247424);                // 33554432 B  -> total 119801856 B
  float* out = (float*)d_out;
  // xb (bf16 x, 64 MB) lives in d_out's 128 MB; consumed by proj_kernel,
  // then d_out is fully overwritten by out_kernel (stream-ordered).
  u16* xb = (u16*)d_out;

  prep_xb<<<16384, 256, 0, stream>>>(x, xb);
  prep_wqkt<<<512, 256, 0, stream>>>(Wqk, Wqkt);
  prep_wvt<<<4096, 256, 0, stream>>>(Wv, Wvt);
  prep_bias<<<1, 512, 0, stream>>>(rel_emb, bias_tab);
  proj_kernel<<<dim3(9, 256), 256, 0, stream>>>(xb, Wqkt, Wvt, bqk, bv, gamma, beta, qm, km, vt);
  score_kernel<<<dim3(8, 64), 256, 0, stream>>>(qm, km, bias_tab, P);
  out_kernel<<<dim3(4, 8, 64), 256, 0, stream>>>(P, vt, out);
}

// Round 3
// 447.458 us; speedup vs baseline: 1.0863x; 1.0427x over previous
//
#include <hip/hip_runtime.h>
#include <hip/hip_bf16.h>

using bf16x8 = __attribute__((ext_vector_type(8))) short;
using f32x4  = __attribute__((ext_vector_type(4))) float;
typedef unsigned short u16;

#define SQRT128 11.313708498984761f
#define NINF (-__builtin_huge_valf())

__device__ __forceinline__ u16 f2bf(float f) {
  unsigned u = __builtin_bit_cast(unsigned, f);
  u += 0x7fffu + ((u >> 16) & 1u);
  return (u16)(u >> 16);
}

__device__ __forceinline__ float swishf(float c) {
  return c / (1.0f + __expf(-c));
}

__device__ __forceinline__ void gld16(const void* g, void* l) {
  __builtin_amdgcn_global_load_lds((const __attribute__((address_space(1))) unsigned*)g,
                                   (__attribute__((address_space(3))) unsigned*)l, 16, 0, 0);
}

// ---------------- prep kernels ----------------
__global__ __launch_bounds__(256) void prep_xb(const float* __restrict__ x,
                                               u16* __restrict__ xb) {
  size_t t = ((size_t)blockIdx.x * 256 + threadIdx.x) * 8;
  float4 f0 = *(const float4*)(x + t);
  float4 f1 = *(const float4*)(x + t + 4);
  uint4 p;
  p.x = f2bf(f0.x) | ((unsigned)f2bf(f0.y) << 16);
  p.y = f2bf(f0.z) | ((unsigned)f2bf(f0.w) << 16);
  p.z = f2bf(f1.x) | ((unsigned)f2bf(f1.y) << 16);
  p.w = f2bf(f1.z) | ((unsigned)f2bf(f1.w) << 16);
  *(uint4*)(xb + t) = p;
}

// W[k][ncols] fp32 -> Wt[n][1024] bf16, via LDS tile transpose (coalesced both sides)
__global__ __launch_bounds__(256) void prep_wt(const float* __restrict__ W,
                                               u16* __restrict__ Wt, int ncols) {
  __shared__ float t[64][65];
  const int tid = threadIdx.x;
  const int k0 = blockIdx.x * 64, n0 = blockIdx.y * 64;
#pragma unroll
  for (int p = 0; p < 16; ++p) {
    const int r = p * 4 + (tid >> 6);
    const int c = tid & 63;
    t[c][r] = W[(size_t)(k0 + r) * ncols + n0 + c];
  }
  __syncthreads();
#pragma unroll
  for (int p = 0; p < 8; ++p) {
    const int n = p * 8 + (tid >> 5);
    const int k2 = (tid & 31) * 2;
    ushort2 pk;
    pk.x = f2bf(t[n][k2]);
    pk.y = f2bf(t[n][k2 + 1]);
    *(ushort2*)&Wt[(size_t)(n0 + n) * 1024 + k0 + k2] = pk;
  }
}

__global__ __launch_bounds__(512) void prep_bias(const float* __restrict__ rel_emb,
                                                 float* __restrict__ bias_tab) {
  int d = threadIdx.x;  // d = i - j >= 0
  int b;
  if (d < 16) {
    b = d;
  } else {
    float v = 16.0f + __logf((float)d * 0.0625f) * (16.0f / 2.0794415416798357f);
    b = (int)v;
    if (b > 31) b = 31;
  }
  bias_tab[d] = rel_emb[b] * SQRT128;
}

// ---------------- fused projection GEMM (m97 structure + XCD swizzle) ----------------
// 1D grid 2304; xcd = bid&7; all 9 nb of an m-panel land on one XCD (L2 reuse of A).
__global__ __launch_bounds__(256, 2) void proj_kernel(
    const u16* __restrict__ xb,
    const u16* __restrict__ Wqkt, const u16* __restrict__ Wvt,
    const float* __restrict__ bqk, const float* __restrict__ bv,
    const float* __restrict__ gamma, const float* __restrict__ beta,
    u16* __restrict__ qm, u16* __restrict__ km, u16* __restrict__ vt) {
  __shared__ u16 a_lds[128 * 64];
  __shared__ u16 b_lds[128 * 64];
  const int bid = blockIdx.x;
  const int xcd = bid & 7;
  const int s = bid >> 3;
  const int mgrp = s / 9;
  const int nb = s - mgrp * 9;
  const int m0 = (mgrp * 8 + xcd) * 128;

  const int tid = threadIdx.x;
  const int lane = tid & 63;
  const int w = tid >> 6;
  const int wm = w >> 1, wn = w & 1;
  const u16* Wt = (nb == 0) ? Wqkt : (Wvt + (size_t)(nb - 1) * 128 * 1024);

  f32x4 acc[4][4];
#pragma unroll
  for (int i = 0; i < 4; i++)
#pragma unroll
    for (int j = 0; j < 4; j++) acc[i][j] = f32x4{0.f, 0.f, 0.f, 0.f};

  const int srow_sub = w * 8 + (lane >> 3);
  const int sbyte = (lane & 7) * 16;

  for (int kt = 0; kt < 16; ++kt) {
    const int k0 = kt * 64;
    __syncthreads();
#pragma unroll
    for (int i = 0; i < 4; ++i) {
      const int row = i * 32 + srow_sub;
      const int colb = sbyte ^ ((row & 7) << 4);
      gld16(xb + (size_t)(m0 + row) * 1024 + k0 + (colb >> 1), &a_lds[(i * 4 + w) * 512]);
      gld16(Wt + (size_t)row * 1024 + k0 + (colb >> 1), &b_lds[(i * 4 + w) * 512]);
    }
    __syncthreads();
#pragma unroll
    for (int kk = 0; kk < 2; ++kk) {
      bf16x8 af[4], bfr[4];
#pragma unroll
      for (int mi = 0; mi < 4; mi++) {
        const int row = wm * 64 + mi * 16 + (lane & 15);
        const int byte_ = (kk * 64 + (lane >> 4) * 16) ^ ((row & 7) << 4);
        af[mi] = *(const bf16x8*)((const char*)a_lds + row * 128 + byte_);
      }
#pragma unroll
      for (int ni = 0; ni < 4; ni++) {
        const int row = wn * 64 + ni * 16 + (lane & 15);
        const int byte_ = (kk * 64 + (lane >> 4) * 16) ^ ((row & 7) << 4);
        bfr[ni] = *(const bf16x8*)((const char*)b_lds + row * 128 + byte_);
      }
#pragma unroll
      for (int mi = 0; mi < 4; mi++)
#pragma unroll
        for (int ni = 0; ni < 4; ni++)
          acc[mi][ni] = __builtin_amdgcn_mfma_f32_16x16x32_bf16(af[mi], bfr[ni], acc[mi][ni], 0, 0, 0);
    }
  }

  if (nb == 0) {
#pragma unroll
    for (int ni = 0; ni < 4; ni++) {
      const int nn = wn * 64 + ni * 16 + (lane & 15);
      const float bb = bqk[nn];
      const float g0 = gamma[nn], g1 = gamma[128 + nn];
      const float be0 = beta[nn], be1 = beta[128 + nn];
#pragma unroll
      for (int mi = 0; mi < 4; mi++) {
#pragma unroll
        for (int r = 0; r < 4; r++) {
          const int m = m0 + wm * 64 + mi * 16 + (lane >> 4) * 4 + r;
          const float sv = swishf(acc[mi][ni][r] + bb);
          qm[(size_t)m * 128 + nn] = f2bf(sv * g0 + be0);
          km[(size_t)m * 128 + nn] = f2bf(sv * g1 + be1);
        }
      }
    }
  } else {
#pragma unroll
    for (int ni = 0; ni < 4; ni++) {
      const int z = (nb - 1) * 128 + wn * 64 + ni * 16 + (lane & 15);
      const float bb = bv[z];
#pragma unroll
      for (int mi = 0; mi < 4; mi++) {
        const int m = m0 + wm * 64 + mi * 16 + (lane >> 4) * 4;
        const int chunkid = m >> 9;
        const int j = m & 511;
        ushort4 pk;
        pk.x = f2bf(swishf(acc[mi][ni][0] + bb));
        pk.y = f2bf(swishf(acc[mi][ni][1] + bb));
        pk.z = f2bf(swishf(acc[mi][ni][2] + bb));
        pk.w = f2bf(swishf(acc[mi][ni][3] + bb));
        *(ushort4*)&vt[((size_t)chunkid * 1024 + z) * 512 + j] = pk;
      }
    }
  }
}

// ---------------- fused scores+softmax+PV ----------------
// 1D grid 512 (chunk->XCD swizzle, qt balanced pairing). 512 threads = 8 waves.
// Phase 1: waves (kh = w>>2, qg = w&3): q-rows qg*16+, k-tile set split by kh.
// P kept in LDS (XOR-swizzled [64]x[128B] tiles). Phase 2: wave w -> out cols w*128..
__global__ __launch_bounds__(512, 1) void attn_kernel(
    const u16* __restrict__ qm, const u16* __restrict__ km,
    const u16* __restrict__ vt, const float* __restrict__ bias_tab,
    float* __restrict__ out) {
  __shared__ char u_lds[65536];       // K bufs 2x16KB aliased under P tiles 8x8KB
  __shared__ float mxbuf[2][64];
  __shared__ float smbuf[2][64];
  __shared__ float lds_bias[512];

  const int bid = blockIdx.x;
  const int xcd = bid & 7;
  const int s = bid >> 3;
  const int ch = (s >> 3) * 8 + xcd;
  const int sq = s & 7;
  const int qt = (sq & 1) ? (sq >> 1) : (7 - (sq >> 1));  // balanced pairs (7,0),(6,1),...

  const int tid = threadIdx.x;
  const int lane = tid & 63;
  const int w = tid >> 6;
  const int g = lane >> 4;
  const int l15 = lane & 15;
  const int qg = w & 3;
  const int kh = w >> 2;

  lds_bias[tid] = bias_tab[tid];

  const int qrow64 = qg * 16 + l15;
  bf16x8 qf[4];
  {
    const u16* qp = qm + ((size_t)(ch * 512 + qt * 64 + qrow64)) * 128 + g * 8;
#pragma unroll
    for (int kk = 0; kk < 4; kk++) qf[kk] = *(const bf16x8*)(qp + kk * 32);
  }

  const int nt = qt + 1;
  const int n0 = (nt + 1) >> 1;
  const int myn = kh ? (nt - n0) : n0;

  f32x4 acc[16];
#pragma unroll
  for (int i = 0; i < 16; i++) acc[i] = f32x4{0.f, 0.f, 0.f, 0.f};

  for (int it = 0; it < n0; ++it) {
    __syncthreads();
#pragma unroll
    for (int b = 0; b < 2; ++b) {
      const int kt = b ? (n0 + it) : it;   // n0+it <= 7 always
#pragma unroll
      for (int i = 0; i < 2; ++i) {
        const int slot = w * 2 + i;
        const int r = slot * 4 + g;
        const int colb = (l15 * 16) ^ ((r & 7) << 4);
        gld16(km + ((size_t)(ch * 512 + kt * 64 + r)) * 128 + (colb >> 1),
              u_lds + b * 16384 + slot * 1024);
      }
    }
    __syncthreads();
    if (!kh || it < nt - n0) {
      const char* kb = u_lds + kh * 16384;
#pragma unroll
      for (int jt = 0; jt < 4; ++jt) {
#pragma unroll
        for (int kk = 0; kk < 4; ++kk) {
          const int row = jt * 16 + l15;
          bf16x8 kf = *(const bf16x8*)(kb + row * 256 + ((kk * 64 + g * 16) ^ ((row & 7) << 4)));
          acc[it * 4 + jt] = __builtin_amdgcn_mfma_f32_16x16x32_bf16(kf, qf[kk], acc[it * 4 + jt], 0, 0, 0);
        }
      }
    }
  }

  // softmax over row ic, cols spread as j = kt*64 + jt*16 + g*4 + r
  const float scale = 0.03125f;
  const int ic = qt * 64 + qrow64;
  float mx = NINF;
#pragma unroll
  for (int it = 0; it < 4; ++it) {
    if (it < myn) {
      const int kt = kh ? (n0 + it) : it;
#pragma unroll
      for (int jt = 0; jt < 4; ++jt) {
#pragma unroll
        for (int r = 0; r < 4; ++r) {
          const int j = kt * 64 + jt * 16 + g * 4 + r;
          int d = ic - j;
          const float bv = lds_bias[d < 0 ? 0 : d];
          const float val = (j <= ic) ? (acc[it * 4 + jt][r] * scale + bv) : NINF;
          acc[it * 4 + jt][r] = val;
          mx = fmaxf(mx, val);
        }
      }
    }
  }
  mx = fmaxf(mx, __shfl_xor(mx, 16));
  mx = fmaxf(mx, __shfl_xor(mx, 32));
  if (g == 0) mxbuf[kh][qrow64] = mx;
  __syncthreads();
  const float M = fmaxf(mx, mxbuf[kh ^ 1][qrow64]);
  float sum = 0.f;
#pragma unroll
  for (int it = 0; it < 4; ++it) {
    if (it < myn) {
#pragma unroll
      for (int jt = 0; jt < 4; ++jt) {
#pragma unroll
        for (int r = 0; r < 4; ++r) {
          const float e = __expf(acc[it * 4 + jt][r] - M);
          acc[it * 4 + jt][r] = e;
          sum += e;
        }
      }
    }
  }
  sum += __shfl_xor(sum, 16);
  sum += __shfl_xor(sum, 32);
  if (g == 0) smbuf[kh][qrow64] = sum;
  __syncthreads();
  const float inv = 1.0f / (sum + smbuf[kh ^ 1][qrow64]);

  // write P tiles (overwrites dead K bufs)
#pragma unroll
  for (int it = 0; it < 4; ++it) {
    if (it < myn) {
      const int kt = kh ? (n0 + it) : it;
      char* pt = u_lds + kt * 8192 + qrow64 * 128;
#pragma unroll
      for (int jt = 0; jt < 4; ++jt) {
        ushort4 pk;
        pk.x = f2bf(acc[it * 4 + jt][0] * inv);
        pk.y = f2bf(acc[it * 4 + jt][1] * inv);
        pk.z = f2bf(acc[it * 4 + jt][2] * inv);
        pk.w = f2bf(acc[it * 4 + jt][3] * inv);
        *(ushort4*)(pt + ((jt * 32 + g * 8) ^ ((qrow64 & 7) << 4))) = pk;
      }
    }
  }
  __syncthreads();

  // phase 2: out[64 x 1024] = P (LDS) @ V (global, L2-resident)
  f32x4 oacc[4][8];
#pragma unroll
  for (int i = 0; i < 4; i++)
#pragma unroll
    for (int j = 0; j < 8; j++) oacc[i][j] = f32x4{0.f, 0.f, 0.f, 0.f};
  const int wcol = w * 128;

  for (int kt = 0; kt <= qt; ++kt) {
    const char* pt = u_lds + kt * 8192;
#pragma unroll
    for (int kk = 0; kk < 2; ++kk) {
      bf16x8 af[4];
#pragma unroll
      for (int mi = 0; mi < 4; ++mi) {
        const int row = mi * 16 + l15;
        af[mi] = *(const bf16x8*)(pt + row * 128 + ((kk * 64 + g * 16) ^ ((row & 7) << 4)));
      }
      const size_t kb = (size_t)kt * 64 + kk * 32 + g * 8;
#pragma unroll
      for (int ni = 0; ni < 8; ++ni) {
        const bf16x8 bfr = *(const bf16x8*)(vt + ((size_t)ch * 1024 + wcol + ni * 16 + l15) * 512 + kb);
#pragma unroll
        for (int mi = 0; mi < 4; ++mi)
          oacc[mi][ni] = __builtin_amdgcn_mfma_f32_16x16x32_bf16(af[mi], bfr, oacc[mi][ni], 0, 0, 0);
      }
    }
  }

  const size_t obase = (size_t)(ch * 512 + qt * 64) * 1024;
#pragma unroll
  for (int mi = 0; mi < 4; ++mi)
#pragma unroll
    for (int ni = 0; ni < 8; ++ni)
#pragma unroll
      for (int r = 0; r < 4; ++r)
        out[obase + (size_t)(mi * 16 + g * 4 + r) * 1024 + wcol + ni * 16 + l15] = oacc[mi][ni][r];
}

// ---------------- launch ----------------
extern "C" void kernel_launch(void* const* d_in, const int* in_sizes, int n_in,
                              void* d_out, int out_size, void* d_ws, size_t ws_size,
                              hipStream_t stream) {
  const float* x = (const float*)d_in[0];
  const float* Wqk = (const float*)d_in[1];
  const float* bqk = (const float*)d_in[2];
  const float* Wv = (const float*)d_in[3];
  const float* bv = (const float*)d_in[4];
  const float* gamma = (const float*)d_in[5];
  const float* beta = (const float*)d_in[6];
  const float* rel_emb = (const float*)d_in[7];

  char* ws = (char*)d_ws;
  u16* Wqkt = (u16*)(ws + 0);                    //   262144 B
  u16* Wvt = (u16*)(ws + 262144);                //  2097152 B
  float* bias_tab = (float*)(ws + 2359296);      //     2048 B
  u16* qm = (u16*)(ws + 2361344);                //  8388608 B
  u16* km = (u16*)(ws + 10749952);               //  8388608 B
  u16* vt = (u16*)(ws + 19138560);               // 67108864 B
  float* out = (float*)d_out;
  // xb (bf16 x, 64 MB) borrows d_out; consumed by proj, overwritten by attn.
  u16* xb = (u16*)d_out;

  prep_xb<<<16384, 256, 0, stream>>>(x, xb);
  prep_wt<<<dim3(16, 2), 256, 0, stream>>>(Wqk, Wqkt, 128);
  prep_wt<<<dim3(16, 16), 256, 0, stream>>>(Wv, Wvt, 1024);
  prep_bias<<<1, 512, 0, stream>>>(rel_emb, bias_tab);
  proj_kernel<<<2304, 256, 0, stream>>>(xb, Wqkt, Wvt, bqk, bv, gamma, beta, qm, km, vt);
  attn_kernel<<<512, 512, 0, stream>>>(qm, km, vt, bias_tab, out);
}